// Round 11
// baseline (319.783 us; speedup 1.0000x reference)
//
#include <hip/hip_runtime.h>
#include <hip/hip_bf16.h>

typedef unsigned short u16;
typedef __attribute__((ext_vector_type(8))) short bf16x8;
typedef __attribute__((ext_vector_type(4))) float f32x4;

#define GLDS16(g, l)                                                        \
  __builtin_amdgcn_global_load_lds(                                         \
      (const __attribute__((address_space(1))) void*)(g),                   \
      (__attribute__((address_space(3))) void*)(l), 16, 0, 0)

__device__ __forceinline__ u16 f2bf(float f) {
  union { float f; unsigned u; } v; v.f = f;
  unsigned r = v.u + 0x7FFFu + ((v.u >> 16) & 1u);
  return (u16)(r >> 16);
}

// Cross-lane reduce over the 4 16-lane rows (lanes l, l^16, l^32, l^48).
// gfx950 permlane*_swap are VALU-rate; fallback __shfl_xor is ds_bpermute.
__device__ __forceinline__ float rowquad_max(float v) {
#if __has_builtin(__builtin_amdgcn_permlane16_swap) && \
    __has_builtin(__builtin_amdgcn_permlane32_swap)
  unsigned u = __builtin_bit_cast(unsigned, v);
  {
    auto r = __builtin_amdgcn_permlane16_swap(u, u, false, false);
    v = fmaxf(__builtin_bit_cast(float, (unsigned)r[0]),
              __builtin_bit_cast(float, (unsigned)r[1]));
  }
  u = __builtin_bit_cast(unsigned, v);
  {
    auto r = __builtin_amdgcn_permlane32_swap(u, u, false, false);
    v = fmaxf(__builtin_bit_cast(float, (unsigned)r[0]),
              __builtin_bit_cast(float, (unsigned)r[1]));
  }
  return v;
#else
  v = fmaxf(v, __shfl_xor(v, 16));
  v = fmaxf(v, __shfl_xor(v, 32));
  return v;
#endif
}

__device__ __forceinline__ float rowquad_sum(float v) {
#if __has_builtin(__builtin_amdgcn_permlane16_swap) && \
    __has_builtin(__builtin_amdgcn_permlane32_swap)
  unsigned u = __builtin_bit_cast(unsigned, v);
  {
    auto r = __builtin_amdgcn_permlane16_swap(u, u, false, false);
    v = __builtin_bit_cast(float, (unsigned)r[0]) +
        __builtin_bit_cast(float, (unsigned)r[1]);
  }
  u = __builtin_bit_cast(unsigned, v);
  {
    auto r = __builtin_amdgcn_permlane32_swap(u, u, false, false);
    v = __builtin_bit_cast(float, (unsigned)r[0]) +
        __builtin_bit_cast(float, (unsigned)r[1]);
  }
  return v;
#else
  v += __shfl_xor(v, 16);
  v += __shfl_xor(v, 32);
  return v;
#endif
}

// ---------------- fused f32 -> bf16 conversion for all 7 inputs ----------
__global__ __launch_bounds__(256) void cvt_all(
    const float4* __restrict__ a0, const float4* __restrict__ a1,
    const float4* __restrict__ a2, const float4* __restrict__ a3,
    const float4* __restrict__ a4, const float4* __restrict__ a5,
    const float4* __restrict__ a6, ushort4* __restrict__ b0,
    ushort4* __restrict__ b1, ushort4* __restrict__ b2,
    ushort4* __restrict__ b3, ushort4* __restrict__ b4,
    ushort4* __restrict__ b5, ushort4* __restrict__ b6) {
  int bid = blockIdx.x;
  const float4* s; ushort4* d; int off;
  if (bid < 4096)       { s = a0; d = b0; off = bid; }
  else if (bid < 8192)  { s = a1; d = b1; off = bid - 4096; }
  else if (bid < 12288) { s = a2; d = b2; off = bid - 8192; }
  else if (bid < 13312) { s = a3; d = b3; off = bid - 12288; }
  else if (bid < 14336) { s = a4; d = b4; off = bid - 13312; }
  else if (bid < 15360) { s = a5; d = b5; off = bid - 14336; }
  else                  { s = a6; d = b6; off = bid - 15360; }
  int i = off * 256 + threadIdx.x;
  float4 v = s[i];
  ushort4 o;
  o.x = f2bf(v.x); o.y = f2bf(v.y); o.z = f2bf(v.z); o.w = f2bf(v.w);
  d[i] = o;
}

// ---------------- NT GEMM core: C[m,n] = sum_k A[m,k] * W[n,k] -----------
template <int MODE>
__device__ __forceinline__ void gemm_core(const u16* __restrict__ A,
                                          const u16* __restrict__ W,
                                          void* __restrict__ C) {
  const int K = 1024;
  __shared__ u16 lds_a[4096];  // 128 rows x 32 cols bf16 (64 B/row)
  __shared__ u16 lds_b[4096];
  const int bn = blockIdx.x, bm = blockIdx.y;
  const int tid = threadIdx.x, l = tid & 63, wid = tid >> 6;
  const int wr = wid >> 1, wc = wid & 1;
  const int l4 = l >> 4, l15 = l & 15;

  f32x4 zero4 = {0.f, 0.f, 0.f, 0.f};
  f32x4 acc[4][4];
  for (int i = 0; i < 4; ++i)
    for (int j = 0; j < 4; ++j) acc[i][j] = zero4;

  const int srow = tid >> 2, scol = (tid & 3) * 8;
  const u16* Ag = A + (bm * 128 + srow) * K + scol;
  const u16* Wg = W + (bn * 128 + srow) * K + scol;
  char* la = (char*)lds_a + wid * 1024;
  char* lb = (char*)lds_b + wid * 1024;

  for (int kt = 0; kt < K; kt += 32) {
    GLDS16(Ag + kt, la);
    GLDS16(Ag + 64 * K + kt, la + 4096);
    GLDS16(Wg + kt, lb);
    GLDS16(Wg + 64 * K + kt, lb + 4096);
    __syncthreads();
    bf16x8 af[4], bf[4];
    for (int i = 0; i < 4; ++i)
      af[i] = *(const bf16x8*)((const char*)lds_a +
                               (wr * 64 + i * 16 + l15) * 64 + l4 * 16);
    for (int j = 0; j < 4; ++j)
      bf[j] = *(const bf16x8*)((const char*)lds_b +
                               (wc * 64 + j * 16 + l15) * 64 + l4 * 16);
    for (int i = 0; i < 4; ++i)
      for (int j = 0; j < 4; ++j)
        acc[i][j] = __builtin_amdgcn_mfma_f32_16x16x32_bf16(af[i], bf[j],
                                                            acc[i][j], 0, 0, 0);
    __syncthreads();
  }

  for (int i = 0; i < 4; ++i)
    for (int j = 0; j < 4; ++j) {
      f32x4 a = acc[i][j];
      for (int r = 0; r < 4; ++r) {
        int m = bm * 128 + wr * 64 + i * 16 + l4 * 4 + r;
        int n = bn * 128 + wc * 64 + j * 16 + l15;
        if (MODE == 0) {
          int bb = m >> 11, srw = m & 2047, h = n >> 6, d = n & 63;
          ((u16*)C)[((bb * 16 + h) * 2048 + srw) * 64 + d] = f2bf(a[r]);
        } else {
          ((float*)C)[m * 1024 + n] = a[r];
        }
      }
    }
}

__global__ __launch_bounds__(256) void gemm_proj(
    const u16* __restrict__ X0, const u16* __restrict__ X1,
    const u16* __restrict__ X2, const u16* __restrict__ W0,
    const u16* __restrict__ W1, const u16* __restrict__ W2,
    u16* __restrict__ O0, u16* __restrict__ O1, u16* __restrict__ O2) {
  int z = blockIdx.z;
  const u16* A = (z == 0) ? X0 : (z == 1) ? X1 : X2;
  const u16* W = (z == 0) ? W0 : (z == 1) ? W1 : W2;
  u16* O = (z == 0) ? O0 : (z == 1) ? O1 : O2;
  gemm_core<0>(A, W, (void*)O);
}

__global__ __launch_bounds__(256) void gemm_out(const u16* __restrict__ A,
                                                const u16* __restrict__ W,
                                                float* __restrict__ C) {
  gemm_core<1>(A, W, (void*)C);
}

// ---------------- V (B,H,S,D) -> V^T (B,H,D,S) ---------------------------
__global__ __launch_bounds__(256) void transpose_v(const u16* __restrict__ Vp,
                                                   u16* __restrict__ Vt) {
  const int st = blockIdx.x, bh = blockIdx.y;
  const int d = threadIdx.x & 63, sg = threadIdx.x >> 6;
  const u16* src = Vp + bh * 131072;
  u16* dst = Vt + bh * 131072;
  const int s0 = st * 64 + sg * 16;
  u16 tmp[16];
  for (int i = 0; i < 16; ++i) tmp[i] = src[(s0 + i) * 64 + d];
  ushort4* o = (ushort4*)(dst + d * 2048 + s0);
  for (int k = 0; k < 4; ++k) {
    ushort4 t4;
    t4.x = tmp[4 * k]; t4.y = tmp[4 * k + 1];
    t4.z = tmp[4 * k + 2]; t4.w = tmp[4 * k + 3];
    o[k] = t4;
  }
}

// ---------------- causal flash attention (split-KV, 2 states/wave) -------
// 2048 blocks x 128 thr. Block = (bh, strip s, pair x). Wave w handles
// state A = (qt=x, KV parity w) and state B = (qt=31-x, parity 1-w):
// ~16.5 tile-iterations per wave, deterministically balanced, two
// independent chains per wave (fused straight-line body -> ILP). Waves
// merge partials (flash-decoding style) via LDS once per strip.
__global__ __launch_bounds__(128, 4) void attn_kernel(
    const u16* __restrict__ Qp, const u16* __restrict__ Kp,
    const u16* __restrict__ Vt, u16* __restrict__ ctx) {
  const int bid = blockIdx.x;
  // XCD swizzle: 2048 blocks / 8 XCDs = 256 contiguous logical per XCD
  // -> each XCD owns 4 whole heads (K/V 2 MB < 4 MiB L2).
  const int logical = ((bid & 7) << 8) | (bid >> 3);
  const int bh = logical >> 6;
  const int rem = logical & 63;
  const int s = rem >> 4, x = rem & 15;
  const int tid = threadIdx.x, w01 = tid >> 6, l = tid & 63;
  const int l4 = l >> 4, l15 = l & 15;

  __shared__ u16 psl[2][2][1024];          // P slabs [wave][state]
  __shared__ float OxA[16][64], OxB[16][64];  // cross-wave O partials
  __shared__ f32x4 mlA[2][2][4], mlB[2][2][4];  // [who][m/l][rowgrp]

  const u16* Qbh = Qp + bh * 131072;   // (S, 64)
  const u16* Kbh = Kp + bh * 131072;   // (S, 64)
  const u16* Vbh = Vt + bh * 131072;   // (64, S)
  const int b = bh >> 4, h = bh & 15;
  u16* ctxb = ctx + (size_t)b * 2048 * 1024 + h * 64;

  const float SCALE2 = 0.03125f * 1.44269504f;  // 1/32 * log2(e)
  const float PEN2 = 144269.5f;                 // 100000 * log2(e)
  const int swz = (l15 & 7) << 4;
  const f32x4 zero4 = {0.f, 0.f, 0.f, 0.f};

  const int pA = w01, pB = 1 - w01;
  const int qtA = x, qtB = 31 - x;
  const int q0A = qtA * 64 + s * 16, q0B = qtB * 64 + s * 16;

  // Q fragments for both states
  const u16* qbA = Qbh + (q0A + l15) * 64 + l4 * 8;
  const bf16x8 bqA0 = *(const bf16x8*)(qbA);
  const bf16x8 bqA1 = *(const bf16x8*)(qbA + 32);
  const u16* qbB = Qbh + (q0B + l15) * 64 + l4 * 8;
  const bf16x8 bqB0 = *(const bf16x8*)(qbB);
  const bf16x8 bqB1 = *(const bf16x8*)(qbB + 32);

  f32x4 accA[4], accB[4];
  for (int g = 0; g < 4; ++g) { accA[g] = zero4; accB[g] = zero4; }
  float mA = -1.0e30f, lA = 0.f, mB = -1.0e30f, lB = 0.f;

  auto BODY = [&](f32x4 (&acc)[4], float& m2, float& lsum, const bf16x8 bq0,
                  const bf16x8 bq1, const int q0, const int t, u16* slab) {
    const int kv0 = t * 64;
    char* pw = (char*)slab;
    // ---- K/V fragment loads ----
    const u16* kb = Kbh + (kv0 + l15) * 64 + l4 * 8;
    bf16x8 kf[8];
#pragma unroll
    for (int g = 0; g < 4; ++g) {
      kf[g] = *(const bf16x8*)(kb + g * 1024);
      kf[g + 4] = *(const bf16x8*)(kb + g * 1024 + 32);
    }
    const u16* vb = Vbh + l15 * 2048 + kv0 + l4 * 8;
    bf16x8 vf[8];
#pragma unroll
    for (int g = 0; g < 4; ++g) {
      vf[g] = *(const bf16x8*)(vb + g * 16 * 2048);
      vf[g + 4] = *(const bf16x8*)(vb + g * 16 * 2048 + 32);
    }
    // ---- QK^T (swapped: lane column = q, regs = kv) ----
    f32x4 sacc[4];
#pragma unroll
    for (int g = 0; g < 4; ++g)
      sacc[g] = __builtin_amdgcn_mfma_f32_16x16x32_bf16(kf[g], bq0, zero4,
                                                        0, 0, 0);
#pragma unroll
    for (int g = 0; g < 4; ++g)
      sacc[g] = __builtin_amdgcn_mfma_f32_16x16x32_bf16(kf[g + 4], bq1,
                                                        sacc[g], 0, 0, 0);
    // ---- scale + causal mask (branchless: kv>q only true on diag tile) --
    const int qk = q0 + l15 - kv0;  // kv > q  <=>  g*16+l4*4+r > qk
    float sv[4][4];
#pragma unroll
    for (int g = 0; g < 4; ++g)
#pragma unroll
      for (int r = 0; r < 4; ++r) {
        int kvl = g * 16 + l4 * 4 + r;
        sv[g][r] = sacc[g][r] * SCALE2 - (kvl > qk ? PEN2 : 0.f);
      }
    // ---- row max (in-lane + VALU-rate cross-row) ----
    float mx = sv[0][0];
#pragma unroll
    for (int g = 0; g < 4; ++g)
#pragma unroll
      for (int r = 0; r < 4; ++r) mx = fmaxf(mx, sv[g][r]);
    mx = rowquad_max(mx);
    const float mnew = fmaxf(m2, mx);
    const float alpha = __builtin_exp2f(m2 - mnew);
    m2 = mnew;
    // ---- alpha broadcast to row-holders (bpermute, hidden under exps) ----
    float aR[4];
#pragma unroll
    for (int r = 0; r < 4; ++r) aR[r] = __shfl(alpha, l4 * 4 + r);
    // ---- p = 2^(s-m), row sum ----
    float p[4][4], rs = 0.f;
#pragma unroll
    for (int g = 0; g < 4; ++g)
#pragma unroll
      for (int r = 0; r < 4; ++r) {
        float e = __builtin_exp2f(sv[g][r] - mnew);
        p[g][r] = e;
        rs += e;
      }
    rs = rowquad_sum(rs);
    lsum = lsum * alpha + rs;
#pragma unroll
    for (int g = 0; g < 4; ++g) {
      f32x4 t4 = acc[g];
      t4[0] *= aR[0]; t4[1] *= aR[1]; t4[2] *= aR[2]; t4[3] *= aR[3];
      acc[g] = t4;
    }
    // ---- P -> bf16 -> LDS (swizzled) -> A-fragments ----
#pragma unroll
    for (int g = 0; g < 4; ++g) {
      ushort4 q4;
      q4.x = f2bf(p[g][0]); q4.y = f2bf(p[g][1]);
      q4.z = f2bf(p[g][2]); q4.w = f2bf(p[g][3]);
      int byte = (l15 * 128 + g * 32 + l4 * 8) ^ swz;
      *(ushort4*)(pw + byte) = q4;
    }
    bf16x8 pa0 = *(const bf16x8*)(pw + ((l15 * 128 + l4 * 16) ^ swz));
    bf16x8 pa1 = *(const bf16x8*)(pw + ((l15 * 128 + 64 + l4 * 16) ^ swz));
    // ---- O += P V ----
#pragma unroll
    for (int g = 0; g < 4; ++g)
      acc[g] = __builtin_amdgcn_mfma_f32_16x16x32_bf16(pa0, vf[g], acc[g],
                                                       0, 0, 0);
#pragma unroll
    for (int g = 0; g < 4; ++g)
      acc[g] = __builtin_amdgcn_mfma_f32_16x16x32_bf16(pa1, vf[g + 4], acc[g],
                                                       0, 0, 0);
  };

  // ---- main loop: phase 1 fused A+B (one BB -> interleaved chains) ----
  const int rAmax = (x - pA) >> 1;          // -1 when x==0 && pA==1
  const int rmax = (31 - x - pB) >> 1;
  int r = 0;
  for (; r <= rAmax; ++r) {
    BODY(accA, mA, lA, bqA0, bqA1, q0A, 2 * r + pA, &psl[w01][0][0]);
    BODY(accB, mB, lB, bqB0, bqB1, q0B, 2 * r + pB, &psl[w01][1][0]);
  }
  for (; r <= rmax; ++r)
    BODY(accB, mB, lB, bqB0, bqB1, q0B, 2 * r + pB, &psl[w01][1][0]);

  // ---- publish partials for the partner wave ----
  if (l < 16) {
    ((float*)&mlA[w01][0][0])[l] = mA;
    ((float*)&mlA[w01][1][0])[l] = lA;
    ((float*)&mlB[w01][0][0])[l] = mB;
    ((float*)&mlB[w01][1][0])[l] = lB;
  }
  if (w01 == 1) {
#pragma unroll
    for (int g = 0; g < 4; ++g)
#pragma unroll
      for (int rr = 0; rr < 4; ++rr) OxA[g * 4 + rr][l] = accA[g][rr];
  } else {
#pragma unroll
    for (int g = 0; g < 4; ++g)
#pragma unroll
      for (int rr = 0; rr < 4; ++rr) OxB[g * 4 + rr][l] = accB[g][rr];
  }
  __syncthreads();

  // ---- merge own partial with partner's, normalize, store ----
  auto MERGE = [&](const f32x4 (&acc)[4], const f32x4 (&ml)[2][2][4],
                   const float* Ox, const int q0) {
    const f32x4 mO = ml[w01][0][l4];
    const f32x4 lO = ml[w01][1][l4];
    const f32x4 mP = ml[w01 ^ 1][0][l4];
    const f32x4 lP = ml[w01 ^ 1][1][l4];
    float wO[4], wP[4], inv[4];
#pragma unroll
    for (int rr = 0; rr < 4; ++rr) {
      float mN = fmaxf(mO[rr], mP[rr]);
      wO[rr] = __builtin_exp2f(mO[rr] - mN);
      wP[rr] = __builtin_exp2f(mP[rr] - mN);
      float ln = lO[rr] * wO[rr] + lP[rr] * wP[rr];
      inv[rr] = 1.f / ln;
    }
#pragma unroll
    for (int rr = 0; rr < 4; ++rr) {
      u16* orow = ctxb + (size_t)(q0 + l4 * 4 + rr) * 1024;
#pragma unroll
      for (int g = 0; g < 4; ++g) {
        float po = Ox[(g * 4 + rr) * 64 + l];
        float val = (acc[g][rr] * wO[rr] + po * wP[rr]) * inv[rr];
        orow[g * 16 + l15] = f2bf(val);
      }
    }
  };
  if (w01 == 0)
    MERGE(accA, mlA, &OxA[0][0], q0A);
  else
    MERGE(accB, mlB, &OxB[0][0], q0B);
}

extern "C" void kernel_launch(void* const* d_in, const int* in_sizes, int n_in,
                              void* d_out, int out_size, void* d_ws,
                              size_t ws_size, hipStream_t stream) {
  (void)in_sizes; (void)n_in; (void)out_size; (void)ws_size;
  const float* key = (const float*)d_in[0];
  const float* query = (const float*)d_in[1];
  const float* value = (const float*)d_in[2];
  const float* Wk = (const float*)d_in[3];
  const float* Wq = (const float*)d_in[4];
  const float* Wv = (const float*)d_in[5];
  const float* Wo = (const float*)d_in[6];

  char* ws = (char*)d_ws;
  u16* keyb = (u16*)(ws + 0);          // 4096x1024 bf16
  u16* qryb = (u16*)(ws + 8388608);
  u16* valb = (u16*)(ws + 16777216);
  u16* Wkb  = (u16*)(ws + 25165824);   // 1024x1024 bf16 each
  u16* Wqb  = (u16*)(ws + 27262976);
  u16* Wvb  = (u16*)(ws + 29360128);
  u16* Wob  = (u16*)(ws + 31457280);
  u16* Kp   = (u16*)(ws + 33554432);   // (B,H,S,D) bf16
  u16* Qp   = (u16*)(ws + 41943040);
  u16* Vp   = (u16*)(ws + 50331648);
  u16* Vt   = (u16*)(ws + 58720256);   // (B,H,D,S) bf16
  u16* ctx  = (u16*)(ws + 67108864);   // (B*S, 1024) bf16

  cvt_all<<<16384, 256, 0, stream>>>(
      (const float4*)key, (const float4*)query, (const float4*)value,
      (const float4*)Wk, (const float4*)Wq, (const float4*)Wv,
      (const float4*)Wo, (ushort4*)keyb, (ushort4*)qryb, (ushort4*)valb,
      (ushort4*)Wkb, (ushort4*)Wqb, (ushort4*)Wvb, (ushort4*)Wob);

  gemm_proj<<<dim3(8, 32, 3), 256, 0, stream>>>(keyb, qryb, valb, Wkb, Wqb,
                                                Wvb, Kp, Qp, Vp);
  transpose_v<<<dim3(32, 32), 256, 0, stream>>>(Vp, Vt);
  attn_kernel<<<2048, 128, 0, stream>>>(Qp, Kp, Vt, ctx);
  gemm_out<<<dim3(8, 32), 256, 0, stream>>>(ctx, Wob, (float*)d_out);
}